// Round 2
// baseline (211.148 us; speedup 1.0000x reference)
//
#include <hip/hip_runtime.h>
#include <hip/hip_bf16.h>
#include <stdint.h>

typedef __attribute__((ext_vector_type(8))) short short8;   // bf16x8 MFMA frag
typedef __attribute__((ext_vector_type(16))) float f32x16;  // 32x32 accumulator

#define NB 8
#define NN 2048
#define NF 128
#define NK 4096

#define LRA 0.1f
#define L2E 1.4426950408889634f

// ---- workspace layout (bytes) ----
#define OFF_HT   0u            // hT[2][8][128][4096] bf16 (col-major h) = 16777216
#define OFF_WCT  16777216u     // WcT[128][128] bf16 (col-major)
#define OFF_WFT  16809984u
#define OFF_WST  16842752u
#define OFF_U1   16875520u     // u1[128] f32 = Wf @ a_q
#define OFF_U2   16876032u     // u2[128] f32 = Wc @ a_k
#define OFF_U3   16876544u     // u3[128] f32 = Wf @ a_k
#define OFF_SQ   16877056u     // sq[2][8][2048] f32
#define OFF_SK   17008128u     // sk[2][8][4096] f32
// total 17270272 (~16.5 MiB)

__device__ __forceinline__ short f2bf(float f){
  __bf16 h = (__bf16)f;                 // RNE, compiler emits v_cvt_pk_bf16_f32 pairs
  return __builtin_bit_cast(short, h);
}
__device__ __forceinline__ short8 pack8(float4 a, float4 b){
  short8 r;
  r[0]=f2bf(a.x); r[1]=f2bf(a.y); r[2]=f2bf(a.z); r[3]=f2bf(a.w);
  r[4]=f2bf(b.x); r[5]=f2bf(b.y); r[6]=f2bf(b.z); r[7]=f2bf(b.w);
  return r;
}

typedef const __attribute__((address_space(1))) unsigned int* gas_t;
typedef __attribute__((address_space(3))) unsigned int* las_t;
__device__ __forceinline__ void gload_lds16(const void* g, void* l){
  // LDS dest is wave-uniform base; HW writes lane i at base + i*16.
  __builtin_amdgcn_global_load_lds((gas_t)g, (las_t)l, 16, 0, 0);
}

// ---------------- kernel 0: weight prep ----------------
// WT[col][k] = bf16(W[k][col]); u1 = Wf@a_q, u2 = Wc@a_k, u3 = Wf@a_k
__global__ __launch_bounds__(256) void k_prep(const float* __restrict__ Wc,
                                              const float* __restrict__ Wf,
                                              const float* __restrict__ Ws,
                                              const float* __restrict__ att,
                                              char* __restrict__ ws){
  short* WcT = (short*)(ws + OFF_WCT);
  short* WfT = (short*)(ws + OFF_WFT);
  short* WsT = (short*)(ws + OFF_WST);
  float* u1  = (float*)(ws + OFF_U1);
  float* u2  = (float*)(ws + OFF_U2);
  float* u3  = (float*)(ws + OFF_U3);
  int t = threadIdx.x;
  for (int e = t; e < NF*NF; e += 256){
    int col = e >> 7, k = e & 127;
    WcT[col*NF + k] = f2bf(Wc[k*NF + col]);
    WfT[col*NF + k] = f2bf(Wf[k*NF + col]);
    WsT[col*NF + k] = f2bf(Ws[k*NF + col]);
  }
  if (t < NF){
    float s1=0.f, s2=0.f, s3=0.f;
    for (int c = 0; c < NF; c++){
      float aq = att[c], ak = att[NF + c];
      float wf = Wf[t*NF + c], wc = Wc[t*NF + c];
      s1 += wf*aq; s2 += wc*ak; s3 += wf*ak;
    }
    u1[t]=s1; u2[t]=s2; u3[t]=s3;
  }
}

// ---------------- kernel 1: build hT (bf16 col-major) + s vectors ----------------
// grid 256 = {xid:2}x{b:8}x{tile:16}; 4 waves x 32 rows = 128 rows/block.
__global__ __launch_bounds__(256) void k_build(const float* __restrict__ x1,
                                               const float* __restrict__ x2,
                                               char* __restrict__ ws){
  int bid = blockIdx.x;
  int xid  = bid >> 7;
  int b    = (bid >> 4) & 7;
  int tile = bid & 15;
  int tid = threadIdx.x, wid = tid >> 6, lane = tid & 63;
  int l31 = lane & 31, khalf = lane >> 5;
  int r0 = tile*128 + wid*32;
  int row = r0 + l31;

  const float* x = xid ? x2 : x1;
  const float* u1 = (const float*)(ws + OFF_U1);
  const float* u2 = (const float*)(ws + OFF_U2);
  const float* u3 = (const float*)(ws + OFF_U3);
  const float* xrow = x + (size_t)(b*NN + row)*NF;

  short8 aF[8];
  float p1=0.f, p2=0.f, p3=0.f;
  #pragma unroll
  for (int ks = 0; ks < 8; ks++){
    int k0 = ks*16 + khalf*8;
    float4 xa = *(const float4*)(xrow + k0);
    float4 xb = *(const float4*)(xrow + k0 + 4);
    float4 a1 = *(const float4*)(u1 + k0), b1 = *(const float4*)(u1 + k0 + 4);
    float4 a2 = *(const float4*)(u2 + k0), b2 = *(const float4*)(u2 + k0 + 4);
    float4 a3 = *(const float4*)(u3 + k0), b3 = *(const float4*)(u3 + k0 + 4);
    p1 += xa.x*a1.x + xa.y*a1.y + xa.z*a1.z + xa.w*a1.w
        + xb.x*b1.x + xb.y*b1.y + xb.z*b1.z + xb.w*b1.w;
    p2 += xa.x*a2.x + xa.y*a2.y + xa.z*a2.z + xa.w*a2.w
        + xb.x*b2.x + xb.y*b2.y + xb.z*b2.z + xb.w*b2.w;
    p3 += xa.x*a3.x + xa.y*a3.y + xa.z*a3.z + xa.w*a3.w
        + xb.x*b3.x + xb.y*b3.y + xb.z*b3.z + xb.w*b3.w;
    aF[ks] = pack8(xa, xb);
  }
  p1 += __shfl_xor(p1, 32);
  p2 += __shfl_xor(p2, 32);
  p3 += __shfl_xor(p3, 32);
  if (lane < 32){
    float* sq = (float*)(ws + OFF_SQ);
    float* sk = (float*)(ws + OFF_SK);
    sq[(xid*NB + b)*NN + row] = p1;                 // s_q of own set
    sk[(xid*NB + b)*NK + NN + row] = p3;            // friend-half s_k of own set
    sk[((1 - xid)*NB + b)*NK + row] = p2;           // cross-half s_k of other set
  }

  short* hT = (short*)(ws + OFF_HT);
  #pragma unroll
  for (int g = 0; g < 2; g++){
    const short* W = g ? (const short*)(ws + OFF_WFT) : (const short*)(ws + OFF_WCT);
    int dset = g ? xid : (1 - xid);
    int kb2  = (g ? NN : 0) + r0;
    f32x16 acc[4] = {};
    #pragma unroll
    for (int ks = 0; ks < 8; ks++){
      #pragma unroll
      for (int cb = 0; cb < 4; cb++){
        short8 bF = *(const short8*)(W + (cb*32 + l31)*NF + ks*16 + khalf*8);
        acc[cb] = __builtin_amdgcn_mfma_f32_32x32x16_bf16(aF[ks], bF, acc[cb], 0, 0, 0);
      }
    }
    short* hbase = hT + (size_t)(dset*NB + b)*NF*NK;
    #pragma unroll
    for (int cb = 0; cb < 4; cb++){
      short* hc = hbase + (size_t)(cb*32 + l31)*NK;
      #pragma unroll
      for (int g4 = 0; g4 < 4; g4++){
        // C/D: col = lane&31, row = (reg&3) + 8*(reg>>2) + 4*(lane>>5)
        int kr = kb2 + g4*8 + khalf*4;
        uint2 v;
        v.x = (unsigned)(unsigned short)f2bf(acc[cb][4*g4+0]) |
              ((unsigned)(unsigned short)f2bf(acc[cb][4*g4+1]) << 16);
        v.y = (unsigned)(unsigned short)f2bf(acc[cb][4*g4+2]) |
              ((unsigned)(unsigned short)f2bf(acc[cb][4*g4+3]) << 16);
        *(uint2*)(hc + kr) = v;
      }
    }
  }
}

// ---------------- kernel 3: fused softmax-weighted GEMM + self ----------------
// grid 256 (XCD-swizzled) = {set:2}x{b:8}x{qt:16}; 4 waves x 32 rows = 128 rows/block.
__global__ __launch_bounds__(256) void k_attn(const float* __restrict__ x1,
                                              const float* __restrict__ x2,
                                              const char* __restrict__ ws,
                                              float* __restrict__ out){
  __shared__ float skb[NK];
  __shared__ __align__(16) char stg[2][16384];   // [col:128][128B of k], XOR-swizzled
  __shared__ float wmax[4];

  int hw = blockIdx.x;
  int bid = (hw & 7)*32 + (hw >> 3);             // XCD-aware swizzle (256 = 8*32)
  int set = bid >> 7, b = (bid >> 4) & 7, qt = bid & 15;
  int tid = threadIdx.x, wid = tid >> 6, lane = tid & 63;
  int l31 = lane & 31, khalf = lane >> 5;

  const short* hT  = (const short*)(ws + OFF_HT) + (size_t)(set*NB + b)*NF*NK;
  const float* skg = (const float*)(ws + OFF_SK) + (set*NB + b)*NK;
  const float* sqg = (const float*)(ws + OFF_SQ) + (set*NB + b)*NN;
  const short* WsT = (const short*)(ws + OFF_WST);

  // stage s_k into LDS + batch max
  float mx = -3.0e38f;
  #pragma unroll
  for (int i = 0; i < 4; i++){
    int idx = i*1024 + tid*4;
    float4 v = *(const float4*)(skg + idx);
    *(float4*)(skb + idx) = v;
    mx = fmaxf(mx, fmaxf(fmaxf(v.x, v.y), fmaxf(v.z, v.w)));
  }
  #pragma unroll
  for (int d = 1; d < 64; d <<= 1) mx = fmaxf(mx, __shfl_xor(mx, d));
  if (lane == 0) wmax[wid] = mx;

  auto stage = [&](int ch, int bi){
    #pragma unroll
    for (int i = 0; i < 4; i++){
      int q = (wid*4 + i)*64 + lane;             // 16B-chunk id 0..1023
      int col = q >> 3, k16 = q & 7;
      int srcc = k16 ^ (col & 7);                // pre-swizzled global source
      gload_lds16((const void*)(hT + col*NK + ch*64 + srcc*8),
                  (void*)&stg[bi][(wid*4 + i)*1024]);
    }
  };
  stage(0, 0);
  __syncthreads();

  float skmax = fmaxf(fmaxf(wmax[0], wmax[1]), fmaxf(wmax[2], wmax[3]));
  int q0w = qt*128 + wid*32;
  int row = q0w + l31;
  float sqv = sqg[row];
  float t0 = sqv + skmax;
  float m = fmaxf(t0, LRA*t0);                   // lrelu monotone => exact row max bound
  float moff = m * L2E;
  int kdiag = NN + row;
  int chd = (NN + q0w) >> 6;
  int ksd = (q0w & 63) >> 4;                     // 0 or 2

  f32x16 acc[4] = {};
  float zacc = 0.f;

  for (int ch = 0; ch < 64; ch++){
    int bi = ch & 1;
    if (ch < 63) stage(ch + 1, bi ^ 1);
    #pragma unroll
    for (int ks = 0; ks < 4; ks++){
      const float* skp = skb + ch*64 + ks*16 + khalf*8;
      float4 sa = *(const float4*)skp;
      float4 sb = *(const float4*)(skp + 4);
      float sv[8] = {sa.x, sa.y, sa.z, sa.w, sb.x, sb.y, sb.z, sb.w};
      float wv[8];
      #pragma unroll
      for (int j = 0; j < 8; j++){
        float t = sqv + sv[j];
        float lr = fmaxf(t, LRA*t);
        wv[j] = __builtin_amdgcn_exp2f(__builtin_fmaf(lr, L2E, -moff));
      }
      if (ch == chd && (ks & ~1) == ksd){        // zero the masked diagonal element
        int kg0 = ch*64 + ks*16 + khalf*8;
        #pragma unroll
        for (int j = 0; j < 8; j++) wv[j] = (kg0 + j == kdiag) ? 0.f : wv[j];
      }
      #pragma unroll
      for (int j = 0; j < 8; j++) zacc += wv[j];
      short8 aw;
      #pragma unroll
      for (int j = 0; j < 8; j++) aw[j] = f2bf(wv[j]);
      #pragma unroll
      for (int cb = 0; cb < 4; cb++){
        int col = cb*32 + l31;
        int slot = (ks*2 + khalf) ^ (col & 7);   // undo staging swizzle
        short8 bF = *(const short8*)&stg[bi][col*128 + slot*16];
        acc[cb] = __builtin_amdgcn_mfma_f32_32x32x16_bf16(aw, bF, acc[cb], 0, 0, 0);
      }
    }
    __syncthreads();
  }

  // finish Z and rescale
  zacc += __shfl_xor(zacc, 32);
  float rz = 1.0f / zacc;
  float rzv[16];
  #pragma unroll
  for (int r = 0; r < 16; r++){
    int rowc = (r & 3) + 8*(r >> 2) + 4*khalf;
    rzv[r] = __shfl(rz, rowc);
  }
  #pragma unroll
  for (int cb = 0; cb < 4; cb++)
    #pragma unroll
    for (int r = 0; r < 16; r++) acc[cb][r] *= rzv[r];

  // fused self GEMM: out += x_q @ Ws
  const float* x = set ? x2 : x1;
  const float* xrow = x + (size_t)(b*NN + row)*NF;
  #pragma unroll
  for (int ks = 0; ks < 8; ks++){
    int k0 = ks*16 + khalf*8;
    float4 xa = *(const float4*)(xrow + k0);
    float4 xb = *(const float4*)(xrow + k0 + 4);
    short8 aF = pack8(xa, xb);
    #pragma unroll
    for (int cb = 0; cb < 4; cb++){
      short8 bF = *(const short8*)(WsT + (cb*32 + l31)*NF + k0);
      acc[cb] = __builtin_amdgcn_mfma_f32_32x32x16_bf16(aF, bF, acc[cb], 0, 0, 0);
    }
  }

  float* op = out + (size_t)(set*NB + b)*NN*NF;
  #pragma unroll
  for (int cb = 0; cb < 4; cb++){
    #pragma unroll
    for (int r = 0; r < 16; r++){
      int rowc = (r & 3) + 8*(r >> 2) + 4*khalf;
      op[(size_t)(q0w + rowc)*NF + cb*32 + l31] = acc[cb][r];
    }
  }
}

extern "C" void kernel_launch(void* const* d_in, const int* in_sizes, int n_in,
                              void* d_out, int out_size, void* d_ws, size_t ws_size,
                              hipStream_t stream){
  const float* x1  = (const float*)d_in[0];
  const float* x2  = (const float*)d_in[1];
  const float* Wc  = (const float*)d_in[2];
  const float* Wf  = (const float*)d_in[3];
  const float* Ws  = (const float*)d_in[4];
  const float* att = (const float*)d_in[5];
  char* ws = (char*)d_ws;
  float* out = (float*)d_out;

  k_prep<<<dim3(1),   dim3(256), 0, stream>>>(Wc, Wf, Ws, att, ws);
  k_build<<<dim3(256), dim3(256), 0, stream>>>(x1, x2, ws);
  k_attn<<<dim3(256), dim3(256), 0, stream>>>(x1, x2, ws, out);
}

// Round 4
// 179.714 us; speedup vs baseline: 1.1749x; 1.1749x over previous
//
#include <hip/hip_runtime.h>
#include <hip/hip_bf16.h>
#include <stdint.h>

typedef __attribute__((ext_vector_type(8))) short short8;   // bf16x8 MFMA frag
typedef __attribute__((ext_vector_type(16))) float f32x16;  // 32x32 accumulator

#define NB 8
#define NN 2048
#define NF 128
#define NK 4096
#define L2E 1.4426950408889634f

// ---- workspace layout (bytes) ----
#define OFF_HT   0u            // hT[2][8][128][4096] bf16 (col-major h) = 16777216
#define OFF_WCT  16777216u     // WcT[128][128] bf16 (col-major)
#define OFF_WFT  16809984u
#define OFF_WST  16842752u
#define OFF_U1   16875520u     // u1[128] f32 = Wf @ a_q
#define OFF_U2   16876032u     // u2[128] f32 = Wc @ a_k
#define OFF_U3   16876544u     // u3[128] f32 = Wf @ a_k
#define OFF_SQ   16877056u     // sq'[2][8][2048] f32  (pre-scaled by log2e)
#define OFF_SK   17008128u     // sk'[2][8][4096] f32  (pre-scaled by log2e)
// total 17270272 (~16.5 MiB)

__device__ __forceinline__ short f2bf(float f){
  __bf16 h = (__bf16)f;
  return __builtin_bit_cast(short, h);
}
__device__ __forceinline__ short8 pack8(float4 a, float4 b){
  short8 r;
  r[0]=f2bf(a.x); r[1]=f2bf(a.y); r[2]=f2bf(a.z); r[3]=f2bf(a.w);
  r[4]=f2bf(b.x); r[5]=f2bf(b.y); r[6]=f2bf(b.z); r[7]=f2bf(b.w);
  return r;
}

typedef const __attribute__((address_space(1))) unsigned int* gas_t;
typedef __attribute__((address_space(3))) unsigned int* las_t;
__device__ __forceinline__ void gload_lds16(const void* g, void* l){
  // LDS dest is wave-uniform base; HW writes lane i at base + i*16.
  __builtin_amdgcn_global_load_lds((gas_t)g, (las_t)l, 16, 0, 0);
}

// ---------------- kernel 0: weight prep (parallel) ----------------
// blocks 0..11: LDS-tiled transpose of {Wc,Wf,Ws} (4 row-tiles of 32 each) to bf16 col-major.
// block 12: u1 = Wf@a_q, u2 = Wc@a_k, u3 = Wf@a_k via coalesced row loads + shfl reduce.
__global__ __launch_bounds__(256) void k_prep(const float* __restrict__ Wc,
                                              const float* __restrict__ Wf,
                                              const float* __restrict__ Ws,
                                              const float* __restrict__ att,
                                              char* __restrict__ ws){
  int bidx = blockIdx.x, tid = threadIdx.x;
  if (bidx < 12){
    __shared__ float tile[32][129];
    int m = bidx >> 2, tno = bidx & 3;
    const float* W = (m == 0) ? Wc : ((m == 1) ? Wf : Ws);
    short* WT = (short*)(ws + ((m == 0) ? OFF_WCT : ((m == 1) ? OFF_WFT : OFF_WST)));
    int r0 = tno*32;
    #pragma unroll
    for (int i = 0; i < 16; i++){
      int e = tid + i*256;
      tile[e >> 7][e & 127] = W[(r0 + (e >> 7))*NF + (e & 127)];
    }
    __syncthreads();
    #pragma unroll
    for (int i = 0; i < 16; i++){
      int o = tid + i*256;
      int col = o >> 5, rr = o & 31;
      WT[col*NF + r0 + rr] = f2bf(tile[rr][col]);
    }
  } else {
    int wid = tid >> 6, lane = tid & 63;
    float aq0 = att[lane],      aq1 = att[64 + lane];
    float ak0 = att[NF + lane], ak1 = att[NF + 64 + lane];
    float* u1 = (float*)(ws + OFF_U1);
    float* u2 = (float*)(ws + OFF_U2);
    float* u3 = (float*)(ws + OFF_U3);
    for (int j = 0; j < 32; j++){
      int r = wid*32 + j;
      float wf0 = Wf[r*NF + lane], wf1 = Wf[r*NF + 64 + lane];
      float wc0 = Wc[r*NF + lane], wc1 = Wc[r*NF + 64 + lane];
      float s1 = wf0*aq0 + wf1*aq1;
      float s2 = wc0*ak0 + wc1*ak1;
      float s3 = wf0*ak0 + wf1*ak1;
      #pragma unroll
      for (int d = 1; d < 64; d <<= 1){
        s1 += __shfl_xor(s1, d); s2 += __shfl_xor(s2, d); s3 += __shfl_xor(s3, d);
      }
      if (lane == 0){ u1[r] = s1; u2[r] = s2; u3[r] = s3; }
    }
  }
}

// ---------------- kernel 1: build hT (bf16 col-major) + scaled s vectors ----------------
__global__ __launch_bounds__(256) void k_build(const float* __restrict__ x1,
                                               const float* __restrict__ x2,
                                               char* __restrict__ ws){
  int bid = blockIdx.x;
  int xid  = bid >> 7;
  int b    = (bid >> 4) & 7;
  int tile = bid & 15;
  int tid = threadIdx.x, wid = tid >> 6, lane = tid & 63;
  int l31 = lane & 31, khalf = lane >> 5;
  int r0 = tile*128 + wid*32;
  int row = r0 + l31;

  const float* x = xid ? x2 : x1;
  const float* u1 = (const float*)(ws + OFF_U1);
  const float* u2 = (const float*)(ws + OFF_U2);
  const float* u3 = (const float*)(ws + OFF_U3);
  const float* xrow = x + (size_t)(b*NN + row)*NF;

  short8 aF[8];
  float p1=0.f, p2=0.f, p3=0.f;
  #pragma unroll
  for (int ks = 0; ks < 8; ks++){
    int k0 = ks*16 + khalf*8;
    float4 xa = *(const float4*)(xrow + k0);
    float4 xb = *(const float4*)(xrow + k0 + 4);
    float4 a1 = *(const float4*)(u1 + k0), b1 = *(const float4*)(u1 + k0 + 4);
    float4 a2 = *(const float4*)(u2 + k0), b2 = *(const float4*)(u2 + k0 + 4);
    float4 a3 = *(const float4*)(u3 + k0), b3 = *(const float4*)(u3 + k0 + 4);
    p1 += xa.x*a1.x + xa.y*a1.y + xa.z*a1.z + xa.w*a1.w
        + xb.x*b1.x + xb.y*b1.y + xb.z*b1.z + xb.w*b1.w;
    p2 += xa.x*a2.x + xa.y*a2.y + xa.z*a2.z + xa.w*a2.w
        + xb.x*b2.x + xb.y*b2.y + xb.z*b2.z + xb.w*b2.w;
    p3 += xa.x*a3.x + xa.y*a3.y + xa.z*a3.z + xa.w*a3.w
        + xb.x*b3.x + xb.y*b3.y + xb.z*b3.z + xb.w*b3.w;
    aF[ks] = pack8(xa, xb);
  }
  p1 += __shfl_xor(p1, 32);
  p2 += __shfl_xor(p2, 32);
  p3 += __shfl_xor(p3, 32);
  if (lane < 32){
    float* sq = (float*)(ws + OFF_SQ);
    float* sk = (float*)(ws + OFF_SK);
    sq[(xid*NB + b)*NN + row] = p1*L2E;            // s_q' of own set
    sk[(xid*NB + b)*NK + NN + row] = p3*L2E;       // friend-half s_k' of own set
    sk[((1 - xid)*NB + b)*NK + row] = p2*L2E;      // cross-half s_k' of other set
  }

  short* hT = (short*)(ws + OFF_HT);
  #pragma unroll
  for (int g = 0; g < 2; g++){
    const short* W = g ? (const short*)(ws + OFF_WFT) : (const short*)(ws + OFF_WCT);
    int dset = g ? xid : (1 - xid);
    int kb2  = (g ? NN : 0) + r0;
    f32x16 acc[4] = {};
    #pragma unroll
    for (int ks = 0; ks < 8; ks++){
      #pragma unroll
      for (int cb = 0; cb < 4; cb++){
        short8 bF = *(const short8*)(W + (cb*32 + l31)*NF + ks*16 + khalf*8);
        acc[cb] = __builtin_amdgcn_mfma_f32_32x32x16_bf16(aF[ks], bF, acc[cb], 0, 0, 0);
      }
    }
    short* hbase = hT + (size_t)(dset*NB + b)*NF*NK;
    #pragma unroll
    for (int cb = 0; cb < 4; cb++){
      short* hc = hbase + (size_t)(cb*32 + l31)*NK;
      #pragma unroll
      for (int g4 = 0; g4 < 4; g4++){
        int kr = kb2 + g4*8 + khalf*4;
        uint2 v;
        v.x = (unsigned)(unsigned short)f2bf(acc[cb][4*g4+0]) |
              ((unsigned)(unsigned short)f2bf(acc[cb][4*g4+1]) << 16);
        v.y = (unsigned)(unsigned short)f2bf(acc[cb][4*g4+2]) |
              ((unsigned)(unsigned short)f2bf(acc[cb][4*g4+3]) << 16);
        *(uint2*)(hc + kr) = v;
      }
    }
  }
}

// ---------------- kernel 2: fused softmax-weighted GEMM + self ----------------
// 512 threads = 2 k-groups x 4 row-waves. 3-buffer counted-vmcnt pipeline per group.
__global__ __launch_bounds__(512) void k_attn(const float* __restrict__ x1,
                                              const float* __restrict__ x2,
                                              const char* __restrict__ ws,
                                              float* __restrict__ out){
  __shared__ float skb[NK];                       // 16KB scaled s_k'
  __shared__ __align__(16) char stg[6*16384];     // 2 groups x 3 bufs x 16KB
  __shared__ float wmax[8];

  int hw = blockIdx.x;
  int bid = (hw & 7)*32 + (hw >> 3);              // XCD-aware swizzle (256 = 8*32)
  int set = bid >> 7, b = (bid >> 4) & 7, qt = bid & 15;
  int tid = threadIdx.x, wid = tid >> 6, lane = tid & 63;
  int grp = wid >> 2, rw = wid & 3;
  int l31 = lane & 31, khalf = lane >> 5;

  const short* hT  = (const short*)(ws + OFF_HT) + (size_t)(set*NB + b)*NF*NK;
  const float* skg = (const float*)(ws + OFF_SK) + (set*NB + b)*NK;
  const float* sqg = (const float*)(ws + OFF_SQ) + (set*NB + b)*NN;
  const short* WsT = (const short*)(ws + OFF_WST);

  auto stage = [&](int li, int bufi){
    char* dst = stg + (grp*3 + bufi)*16384;
    int ch = grp*32 + li;
    #pragma unroll
    for (int i = 0; i < 4; i++){
      int q = (rw*4 + i)*64 + lane;               // 16B-chunk id 0..1023
      int col = q >> 3, k16 = q & 7;
      int srcc = k16 ^ (col & 7);                 // pre-swizzled global source
      gload_lds16((const void*)(hT + col*NK + ch*64 + srcc*8),
                  (void*)(dst + (rw*4 + i)*1024));
    }
  };

  // prologue: prefetch 2 chunks per group, stage s_k' + batch max
  stage(0, 0);
  stage(1, 1);
  float mx = -3.0e38f;
  #pragma unroll
  for (int i = 0; i < 2; i++){
    int idx = i*2048 + tid*4;
    float4 v = *(const float4*)(skg + idx);
    *(float4*)(skb + idx) = v;
    mx = fmaxf(mx, fmaxf(fmaxf(v.x, v.y), fmaxf(v.z, v.w)));
  }
  #pragma unroll
  for (int d = 1; d < 64; d <<= 1) mx = fmaxf(mx, __shfl_xor(mx, d));
  if (lane == 0) wmax[wid] = mx;
  asm volatile("s_waitcnt lgkmcnt(0)" ::: "memory");  // skb/wmax writes done (vmcnt NOT drained)
  asm volatile("s_barrier" ::: "memory");

  float skmax = wmax[0];
  #pragma unroll
  for (int i = 1; i < 8; i++) skmax = fmaxf(skmax, wmax[i]);

  int q0w = qt*128 + rw*32;
  int row = q0w + l31;
  float sqv = sqg[row];                            // sq' (scaled)
  float t0 = sqv + skmax;
  float moff = fmaxf(t0, 0.1f*t0);                 // exact row max of lrelu (scaled)
  float sqm = sqv - moff;
  float c9  = -0.9f*moff;
  int kdiag = NN + row;
  int chd = (NN + q0w) >> 6;                       // diag chunk is always in group 1
  int ksd = (q0w & 63) >> 4;

  f32x16 acc[4] = {};
  float zacc = 0.f;

  int bs = 2, bc = 0;
  for (int it = 0; it < 32; ++it){
    if (it < 30){
      stage(it + 2, bs);
      asm volatile("s_waitcnt vmcnt(8)" ::: "memory");   // retire chunk `it`'s 4 loads
    } else if (it == 30){
      asm volatile("s_waitcnt vmcnt(4)" ::: "memory");
    } else {
      asm volatile("s_waitcnt vmcnt(0)" ::: "memory");
    }
    asm volatile("s_barrier" ::: "memory");

    int ch = grp*32 + it;
    const char* buf = stg + (grp*3 + bc)*16384;
    #pragma unroll
    for (int ks = 0; ks < 4; ks++){
      const float* skp = skb + ch*64 + ks*16 + khalf*8;
      float wv[8];
      #pragma unroll
      for (int j = 0; j < 8; j++){
        float p = skp[j] + sqm;                    // t' - moff
        float qn = __builtin_fmaf(0.1f, p, c9);    // 0.1 t' - moff
        wv[j] = __builtin_amdgcn_exp2f(fmaxf(p, qn));
      }
      if (ch == chd && (ks & ~1) == ksd){          // zero masked diagonal element
        int kg0 = ch*64 + ks*16 + khalf*8;
        #pragma unroll
        for (int j = 0; j < 8; j++) wv[j] = (kg0 + j == kdiag) ? 0.f : wv[j];
      }
      #pragma unroll
      for (int j = 0; j < 8; j++) zacc += wv[j];
      short8 aw;
      #pragma unroll
      for (int j = 0; j < 8; j++) aw[j] = f2bf(wv[j]);
      #pragma unroll
      for (int cb = 0; cb < 4; cb++){
        int col = cb*32 + l31;
        int slot = (ks*2 + khalf) ^ (col & 7);     // undo staging swizzle
        short8 bF = *(const short8*)(buf + col*128 + slot*16);
        acc[cb] = __builtin_amdgcn_mfma_f32_32x32x16_bf16(aw, bF, acc[cb], 0, 0, 0);
      }
    }
    asm volatile("s_barrier" ::: "memory");
    bs = (bs == 2) ? 0 : bs + 1;
    bc = (bc == 2) ? 0 : bc + 1;
  }

  // cross-group combine (group1 -> LDS -> group0)
  float* xch = (float*)stg;                        // [64][256] reuse, conflict-free layout
  float* zx  = skb;                                // reuse
  if (grp == 1){
    #pragma unroll
    for (int cb = 0; cb < 4; cb++)
      #pragma unroll
      for (int r = 0; r < 16; r++)
        xch[(cb*16 + r)*256 + rw*64 + lane] = acc[cb][r];
    zx[rw*64 + lane] = zacc;
  }
  __syncthreads();
  if (grp == 0){
    #pragma unroll
    for (int cb = 0; cb < 4; cb++)
      #pragma unroll
      for (int r = 0; r < 16; r++)
        acc[cb][r] += xch[(cb*16 + r)*256 + rw*64 + lane];
    zacc += zx[rw*64 + lane];
    zacc += __shfl_xor(zacc, 32);
    float rz = 1.0f / zacc;
    float rzv[16];
    #pragma unroll
    for (int r = 0; r < 16; r++){
      int rowc = (r & 3) + 8*(r >> 2) + 4*khalf;
      rzv[r] = __shfl(rz, rowc);
    }
    #pragma unroll
    for (int cb = 0; cb < 4; cb++)
      #pragma unroll
      for (int r = 0; r < 16; r++) acc[cb][r] *= rzv[r];

    // fused self GEMM: out += x_q @ Ws
    const float* x = set ? x2 : x1;
    const float* xrow = x + (size_t)(b*NN + row)*NF;
    #pragma unroll
    for (int ks8 = 0; ks8 < 8; ks8++){
      int k0 = ks8*16 + khalf*8;
      float4 xa = *(const float4*)(xrow + k0);
      float4 xb = *(const float4*)(xrow + k0 + 4);
      short8 aF = pack8(xa, xb);
      #pragma unroll
      for (int cb = 0; cb < 4; cb++){
        short8 bF = *(const short8*)(WsT + (cb*32 + l31)*NF + k0);
        acc[cb] = __builtin_amdgcn_mfma_f32_32x32x16_bf16(aF, bF, acc[cb], 0, 0, 0);
      }
    }
    float* op = out + (size_t)(set*NB + b)*NN*NF;
    #pragma unroll
    for (int cb = 0; cb < 4; cb++){
      #pragma unroll
      for (int r = 0; r < 16; r++){
        int rowc = (r & 3) + 8*(r >> 2) + 4*khalf;
        op[(size_t)(q0w + rowc)*NF + cb*32 + l31] = acc[cb][r];
      }
    }
  }
}

extern "C" void kernel_launch(void* const* d_in, const int* in_sizes, int n_in,
                              void* d_out, int out_size, void* d_ws, size_t ws_size,
                              hipStream_t stream){
  const float* x1  = (const float*)d_in[0];
  const float* x2  = (const float*)d_in[1];
  const float* Wc  = (const float*)d_in[2];
  const float* Wf  = (const float*)d_in[3];
  const float* Ws  = (const float*)d_in[4];
  const float* att = (const float*)d_in[5];
  char* ws = (char*)d_ws;
  float* out = (float*)d_out;

  k_prep<<<dim3(13),  dim3(256), 0, stream>>>(Wc, Wf, Ws, att, ws);
  k_build<<<dim3(256), dim3(256), 0, stream>>>(x1, x2, ws);
  k_attn<<<dim3(256), dim3(512), 0, stream>>>(x1, x2, ws, out);
}

// Round 6
// 171.872 us; speedup vs baseline: 1.2285x; 1.0456x over previous
//
#include <hip/hip_runtime.h>
#include <hip/hip_bf16.h>
#include <stdint.h>

typedef __attribute__((ext_vector_type(8))) short short8;   // bf16x8 MFMA frag
typedef __attribute__((ext_vector_type(16))) float f32x16;  // 32x32 accumulator

#define NB 8
#define NN 2048
#define NF 128
#define NK 4096
#define L2E 1.4426950408889634f

// ---- workspace layout (bytes) ----
#define OFF_HT   0u            // hT[2][8][128][4096] bf16 (col-major h) = 16777216
#define OFF_WCT  16777216u     // WcT[128][128] bf16 (col-major)
#define OFF_WFT  16809984u
#define OFF_WST  16842752u
#define OFF_U1   16875520u     // u1[128] f32 = Wf @ a_q
#define OFF_U2   16876032u     // u2[128] f32 = Wc @ a_k
#define OFF_U3   16876544u     // u3[128] f32 = Wf @ a_k
#define OFF_SQ   16877056u     // sq'[2][8][2048] f32  (pre-scaled by log2e)
#define OFF_SK   17008128u     // sk'[2][8][4096] f32  (pre-scaled by log2e)
// total 17270272 (~16.5 MiB)

__device__ __forceinline__ short f2bf(float f){
  __bf16 h = (__bf16)f;
  return __builtin_bit_cast(short, h);
}
__device__ __forceinline__ short8 pack8(float4 a, float4 b){
  short8 r;
  r[0]=f2bf(a.x); r[1]=f2bf(a.y); r[2]=f2bf(a.z); r[3]=f2bf(a.w);
  r[4]=f2bf(b.x); r[5]=f2bf(b.y); r[6]=f2bf(b.z); r[7]=f2bf(b.w);
  return r;
}

typedef const __attribute__((address_space(1))) unsigned int* gas_t;
typedef __attribute__((address_space(3))) unsigned int* las_t;
__device__ __forceinline__ void gload_lds16(const void* g, void* l){
  // LDS dest is wave-uniform base; HW writes lane i at base + i*16.
  __builtin_amdgcn_global_load_lds((gas_t)g, (las_t)l, 16, 0, 0);
}

// ---------------- kernel 0: weight prep (parallel) ----------------
__global__ __launch_bounds__(256) void k_prep(const float* __restrict__ Wc,
                                              const float* __restrict__ Wf,
                                              const float* __restrict__ Ws,
                                              const float* __restrict__ att,
                                              char* __restrict__ ws){
  int bidx = blockIdx.x, tid = threadIdx.x;
  if (bidx < 12){
    __shared__ float tile[32][129];
    int m = bidx >> 2, tno = bidx & 3;
    const float* W = (m == 0) ? Wc : ((m == 1) ? Wf : Ws);
    short* WT = (short*)(ws + ((m == 0) ? OFF_WCT : ((m == 1) ? OFF_WFT : OFF_WST)));
    int r0 = tno*32;
    #pragma unroll
    for (int i = 0; i < 16; i++){
      int e = tid + i*256;
      tile[e >> 7][e & 127] = W[(r0 + (e >> 7))*NF + (e & 127)];
    }
    __syncthreads();
    #pragma unroll
    for (int i = 0; i < 16; i++){
      int o = tid + i*256;
      int col = o >> 5, rr = o & 31;
      WT[col*NF + r0 + rr] = f2bf(tile[rr][col]);
    }
  } else {
    int wid = tid >> 6, lane = tid & 63;
    float aq0 = att[lane],      aq1 = att[64 + lane];
    float ak0 = att[NF + lane], ak1 = att[NF + 64 + lane];
    float* u1 = (float*)(ws + OFF_U1);
    float* u2 = (float*)(ws + OFF_U2);
    float* u3 = (float*)(ws + OFF_U3);
    for (int j = 0; j < 32; j++){
      int r = wid*32 + j;
      float wf0 = Wf[r*NF + lane], wf1 = Wf[r*NF + 64 + lane];
      float wc0 = Wc[r*NF + lane], wc1 = Wc[r*NF + 64 + lane];
      float s1 = wf0*aq0 + wf1*aq1;
      float s2 = wc0*ak0 + wc1*ak1;
      float s3 = wf0*ak0 + wf1*ak1;
      #pragma unroll
      for (int d = 1; d < 64; d <<= 1){
        s1 += __shfl_xor(s1, d); s2 += __shfl_xor(s2, d); s3 += __shfl_xor(s3, d);
      }
      if (lane == 0){ u1[r] = s1; u2[r] = s2; u3[r] = s3; }
    }
  }
}

// ---------------- kernel 1: build hT (bf16 col-major) + scaled s vectors ----------------
__global__ __launch_bounds__(256) void k_build(const float* __restrict__ x1,
                                               const float* __restrict__ x2,
                                               char* __restrict__ ws){
  int bid = blockIdx.x;
  int xid  = bid >> 7;
  int b    = (bid >> 4) & 7;
  int tile = bid & 15;
  int tid = threadIdx.x, wid = tid >> 6, lane = tid & 63;
  int l31 = lane & 31, khalf = lane >> 5;
  int r0 = tile*128 + wid*32;
  int row = r0 + l31;

  const float* x = xid ? x2 : x1;
  const float* u1 = (const float*)(ws + OFF_U1);
  const float* u2 = (const float*)(ws + OFF_U2);
  const float* u3 = (const float*)(ws + OFF_U3);
  const float* xrow = x + (size_t)(b*NN + row)*NF;

  short8 aF[8];
  float p1=0.f, p2=0.f, p3=0.f;
  #pragma unroll
  for (int ks = 0; ks < 8; ks++){
    int k0 = ks*16 + khalf*8;
    float4 xa = *(const float4*)(xrow + k0);
    float4 xb = *(const float4*)(xrow + k0 + 4);
    float4 a1 = *(const float4*)(u1 + k0), b1 = *(const float4*)(u1 + k0 + 4);
    float4 a2 = *(const float4*)(u2 + k0), b2 = *(const float4*)(u2 + k0 + 4);
    float4 a3 = *(const float4*)(u3 + k0), b3 = *(const float4*)(u3 + k0 + 4);
    p1 += xa.x*a1.x + xa.y*a1.y + xa.z*a1.z + xa.w*a1.w
        + xb.x*b1.x + xb.y*b1.y + xb.z*b1.z + xb.w*b1.w;
    p2 += xa.x*a2.x + xa.y*a2.y + xa.z*a2.z + xa.w*a2.w
        + xb.x*b2.x + xb.y*b2.y + xb.z*b2.z + xb.w*b2.w;
    p3 += xa.x*a3.x + xa.y*a3.y + xa.z*a3.z + xa.w*a3.w
        + xb.x*b3.x + xb.y*b3.y + xb.z*b3.z + xb.w*b3.w;
    aF[ks] = pack8(xa, xb);
  }
  p1 += __shfl_xor(p1, 32);
  p2 += __shfl_xor(p2, 32);
  p3 += __shfl_xor(p3, 32);
  if (lane < 32){
    float* sq = (float*)(ws + OFF_SQ);
    float* sk = (float*)(ws + OFF_SK);
    sq[(xid*NB + b)*NN + row] = p1*L2E;            // s_q' of own set
    sk[(xid*NB + b)*NK + NN + row] = p3*L2E;       // friend-half s_k' of own set
    sk[((1 - xid)*NB + b)*NK + row] = p2*L2E;      // cross-half s_k' of other set
  }

  short* hT = (short*)(ws + OFF_HT);
  #pragma unroll
  for (int g = 0; g < 2; g++){
    const short* W = g ? (const short*)(ws + OFF_WFT) : (const short*)(ws + OFF_WCT);
    int dset = g ? xid : (1 - xid);
    int kb2  = (g ? NN : 0) + r0;
    f32x16 acc[4] = {};
    #pragma unroll
    for (int ks = 0; ks < 8; ks++){
      #pragma unroll
      for (int cb = 0; cb < 4; cb++){
        short8 bF = *(const short8*)(W + (cb*32 + l31)*NF + ks*16 + khalf*8);
        acc[cb] = __builtin_amdgcn_mfma_f32_32x32x16_bf16(aF[ks], bF, acc[cb], 0, 0, 0);
      }
    }
    short* hbase = hT + (size_t)(dset*NB + b)*NF*NK;
    #pragma unroll
    for (int cb = 0; cb < 4; cb++){
      short* hc = hbase + (size_t)(cb*32 + l31)*NK;
      #pragma unroll
      for (int g4 = 0; g4 < 4; g4++){
        int kr = kb2 + g4*8 + khalf*4;
        uint2 v;
        v.x = (unsigned)(unsigned short)f2bf(acc[cb][4*g4+0]) |
              ((unsigned)(unsigned short)f2bf(acc[cb][4*g4+1]) << 16);
        v.y = (unsigned)(unsigned short)f2bf(acc[cb][4*g4+2]) |
              ((unsigned)(unsigned short)f2bf(acc[cb][4*g4+3]) << 16);
        *(uint2*)(hc + kr) = v;
      }
    }
  }
}

// ---------------- kernel 2: fused softmax-weighted GEMM + self ----------------
// 512 threads = 4 k-groups x 2 row-waves x 64 rows. Each bF feeds 2 MFMAs (acc[2][4]).
// Double-buffered stages, counted vmcnt; 4-way LDS combine tree; epilogue on grp0.
__global__ __launch_bounds__(512, 2) void k_attn(const float* __restrict__ x1,
                                              const float* __restrict__ x2,
                                              const char* __restrict__ ws,
                                              float* __restrict__ out){
  __shared__ float skb[NK];                       // 16KB scaled s_k'
  __shared__ __align__(16) char stg[8*16384];     // 4 grp x 2 bufs x 16KB
  __shared__ float wmax[8];

  int hw = blockIdx.x;
  int bid = (hw & 7)*32 + (hw >> 3);              // XCD-aware swizzle (256 = 8*32)
  int set = bid >> 7, b = (bid >> 4) & 7, qt = bid & 15;
  int tid = threadIdx.x, wid = tid >> 6, lane = tid & 63;
  int grp = wid >> 1, rw = wid & 1;
  int l31 = lane & 31, khalf = lane >> 5;

  const short* hT  = (const short*)(ws + OFF_HT) + (size_t)(set*NB + b)*NF*NK;
  const float* skg = (const float*)(ws + OFF_SK) + (set*NB + b)*NK;
  const float* sqg = (const float*)(ws + OFF_SQ) + (set*NB + b)*NN;
  const short* WsT = (const short*)(ws + OFF_WST);

  auto stage = [&](int it, int bufi){
    char* dst = stg + (grp*2 + bufi)*16384;
    int ch = grp*16 + it;
    #pragma unroll
    for (int i = 0; i < 8; i++){
      int u = (rw*8 + i)*64 + lane;               // 16B-chunk id 0..1023
      int col = u >> 3, k16 = u & 7;
      int srcc = k16 ^ (col & 7);                 // pre-swizzled global source
      gload_lds16((const void*)(hT + col*NK + ch*64 + srcc*8),
                  (void*)(dst + (rw*8 + i)*1024));
    }
  };

  stage(0, 0);
  float mx = -3.0e38f;
  #pragma unroll
  for (int i = 0; i < 2; i++){
    int idx = i*2048 + tid*4;
    float4 v = *(const float4*)(skg + idx);
    *(float4*)(skb + idx) = v;
    mx = fmaxf(mx, fmaxf(fmaxf(v.x, v.y), fmaxf(v.z, v.w)));
  }
  #pragma unroll
  for (int d = 1; d < 64; d <<= 1) mx = fmaxf(mx, __shfl_xor(mx, d));
  if (lane == 0) wmax[wid] = mx;
  asm volatile("s_waitcnt lgkmcnt(0)" ::: "memory");  // LDS writes done (vmcnt NOT drained)
  asm volatile("s_barrier" ::: "memory");

  float skmax = wmax[0];
  #pragma unroll
  for (int i = 1; i < 8; i++) skmax = fmaxf(skmax, wmax[i]);

  int q0w = qt*128 + rw*64;
  float sqm[2], c9[2]; int kdiag[2];
  #pragma unroll
  for (int rb = 0; rb < 2; rb++){
    int row = q0w + rb*32 + l31;
    float sqv = sqg[row];                          // sq' (scaled)
    float t0 = sqv + skmax;
    float moff = fmaxf(t0, 0.1f*t0);               // exact row max of lrelu (scaled)
    sqm[rb] = sqv - moff;
    c9[rb]  = -0.9f*moff;
    kdiag[rb] = NN + row;
  }
  int chd = (NN + q0w) >> 6;                       // single diag chunk per wave

  f32x16 acc[2][4] = {};
  float zacc[2] = {0.f, 0.f};

  for (int it = 0; it < 16; ++it){
    if (it < 15){
      stage(it + 1, (it + 1) & 1);
      asm volatile("s_waitcnt vmcnt(8)" ::: "memory");   // retire chunk it's 8 loads
    } else {
      asm volatile("s_waitcnt vmcnt(0)" ::: "memory");
    }
    asm volatile("s_barrier" ::: "memory");

    int ch = grp*16 + it;
    const char* buf = stg + (grp*2 + (it & 1))*16384;
    #pragma unroll
    for (int ks = 0; ks < 4; ks++){
      const float* skp = skb + ch*64 + ks*16 + khalf*8;
      float sv[8];
      #pragma unroll
      for (int j = 0; j < 8; j++) sv[j] = skp[j];
      short8 aw[2];
      #pragma unroll
      for (int rb = 0; rb < 2; rb++){
        float wv[8];
        #pragma unroll
        for (int j = 0; j < 8; j++){
          float p = sv[j] + sqm[rb];                 // t' - moff
          float qn = __builtin_fmaf(0.1f, p, c9[rb]); // 0.1 t' - moff
          wv[j] = __builtin_amdgcn_exp2f(fmaxf(p, qn));
        }
        if (ch == chd){                              // zero masked diagonal element
          int kg0 = ch*64 + ks*16 + khalf*8;
          #pragma unroll
          for (int j = 0; j < 8; j++) wv[j] = (kg0 + j == kdiag[rb]) ? 0.f : wv[j];
        }
        #pragma unroll
        for (int j = 0; j < 8; j++) zacc[rb] += wv[j];
        #pragma unroll
        for (int j = 0; j < 8; j++) aw[rb][j] = f2bf(wv[j]);
      }
      #pragma unroll
      for (int cb = 0; cb < 4; cb++){
        int col = cb*32 + l31;
        int slot = (ks*2 + khalf) ^ (col & 7);       // undo staging swizzle
        short8 bF = *(const short8*)(buf + col*128 + slot*16);
        acc[0][cb] = __builtin_amdgcn_mfma_f32_32x32x16_bf16(aw[0], bF, acc[0][cb], 0, 0, 0);
        acc[1][cb] = __builtin_amdgcn_mfma_f32_32x32x16_bf16(aw[1], bF, acc[1][cb], 0, 0, 0);
      }
    }
    asm volatile("s_barrier" ::: "memory");
  }

  // ---- 4-way combine tree: grp0+=grp1, grp2+=grp3; then grp0+=grp2 ----
  float* cbuf1 = (float*)stg;                      // 64KB
  float* cbuf2 = (float*)(stg + 65536);            // 64KB
  float* zarr  = skb;                              // [wid][rb][64] reuse
  if (grp == 1 || grp == 3){
    float* dst = (grp == 1) ? cbuf1 : cbuf2;
    #pragma unroll
    for (int rb = 0; rb < 2; rb++){
      #pragma unroll
      for (int cb = 0; cb < 4; cb++)
        #pragma unroll
        for (int r = 0; r < 16; r++)
          dst[(((rw*2 + rb)*4 + cb)*16 + r)*64 + lane] = acc[rb][cb][r];
      zarr[(wid*2 + rb)*64 + lane] = zacc[rb];
    }
  }
  __syncthreads();
  if (grp == 0 || grp == 2){
    const float* src = (grp == 0) ? cbuf1 : cbuf2;
    int swid = (grp == 0) ? (2 + rw) : (6 + rw);
    #pragma unroll
    for (int rb = 0; rb < 2; rb++){
      #pragma unroll
      for (int cb = 0; cb < 4; cb++)
        #pragma unroll
        for (int r = 0; r < 16; r++)
          acc[rb][cb][r] += src[(((rw*2 + rb)*4 + cb)*16 + r)*64 + lane];
      zacc[rb] += zarr[(swid*2 + rb)*64 + lane];
    }
  }
  __syncthreads();
  if (grp == 2){
    #pragma unroll
    for (int rb = 0; rb < 2; rb++){
      #pragma unroll
      for (int cb = 0; cb < 4; cb++)
        #pragma unroll
        for (int r = 0; r < 16; r++)
          cbuf1[(((rw*2 + rb)*4 + cb)*16 + r)*64 + lane] = acc[rb][cb][r];
      zarr[((4 + rw)*2 + rb)*64 + lane] = zacc[rb];
    }
  }
  __syncthreads();
  if (grp == 0){
    #pragma unroll
    for (int rb = 0; rb < 2; rb++){
      #pragma unroll
      for (int cb = 0; cb < 4; cb++)
        #pragma unroll
        for (int r = 0; r < 16; r++)
          acc[rb][cb][r] += cbuf1[(((rw*2 + rb)*4 + cb)*16 + r)*64 + lane];
      zacc[rb] += zarr[((4 + rw)*2 + rb)*64 + lane];
    }
    // rescale + fused self GEMM + store
    const float* x = set ? x2 : x1;
    float* op = out + (size_t)(set*NB + b)*NN*NF;
    #pragma unroll
    for (int rb = 0; rb < 2; rb++){
      float zr = zacc[rb] + __shfl_xor(zacc[rb], 32);
      float rz = 1.0f / zr;
      float rzv[16];
      #pragma unroll
      for (int r = 0; r < 16; r++){
        int rowc = (r & 3) + 8*(r >> 2) + 4*khalf;
        rzv[r] = __shfl(rz, rowc);
      }
      #pragma unroll
      for (int cb = 0; cb < 4; cb++)
        #pragma unroll
        for (int r = 0; r < 16; r++) acc[rb][cb][r] *= rzv[r];

      const float* xrow = x + (size_t)(b*NN + q0w + rb*32 + l31)*NF;
      #pragma unroll
      for (int ks8 = 0; ks8 < 8; ks8++){
        int k0 = ks8*16 + khalf*8;
        float4 xa = *(const float4*)(xrow + k0);
        float4 xb = *(const float4*)(xrow + k0 + 4);
        short8 aF = pack8(xa, xb);
        #pragma unroll
        for (int cb = 0; cb < 4; cb++){
          short8 bF = *(const short8*)(WsT + (cb*32 + l31)*NF + k0);
          acc[rb][cb] = __builtin_amdgcn_mfma_f32_32x32x16_bf16(aF, bF, acc[rb][cb], 0, 0, 0);
        }
      }
      #pragma unroll
      for (int cb = 0; cb < 4; cb++)
        #pragma unroll
        for (int r = 0; r < 16; r++){
          int rowc = (r & 3) + 8*(r >> 2) + 4*khalf;
          op[(size_t)(q0w + rb*32 + rowc)*NF + cb*32 + l31] = acc[rb][cb][r];
        }
    }
  }
}

extern "C" void kernel_launch(void* const* d_in, const int* in_sizes, int n_in,
                              void* d_out, int out_size, void* d_ws, size_t ws_size,
                              hipStream_t stream){
  const float* x1  = (const float*)d_in[0];
  const float* x2  = (const float*)d_in[1];
  const float* Wc  = (const float*)d_in[2];
  const float* Wf  = (const float*)d_in[3];
  const float* Ws  = (const float*)d_in[4];
  const float* att = (const float*)d_in[5];
  char* ws = (char*)d_ws;
  float* out = (float*)d_out;

  k_prep<<<dim3(13),  dim3(256), 0, stream>>>(Wc, Wf, Ws, att, ws);
  k_build<<<dim3(256), dim3(256), 0, stream>>>(x1, x2, ws);
  k_attn<<<dim3(256), dim3(512), 0, stream>>>(x1, x2, ws, out);
}